// Round 18
// baseline (94.156 us; speedup 1.0000x reference)
//
#include <hip/hip_runtime.h>
#include <math.h>

namespace {

constexpr int NUM_NEG   = 8;
constexpr int BROWS     = 262144;
constexpr float MARGIN1 = 0.1f;
constexpr float MARGIN2 = 0.1f;
constexpr float TAU     = 0.2f;
constexpr float EPS1    = 1e-7f;
constexpr float MAXNORM = 1.0f - 1e-5f;

// Parity-staggered intra-block fusion: every block does a rank slice AND
// (for b<3000) a cls/cl slice; even blocks rank-first, odd blocks other-first
// -> deterministic ~50/50 resident mix of L3-gather and VALU work.
constexpr int NBLK       = 4096;
constexpr int RANK_WAVES = NBLK * 4;        // 16384; 8 rows/wave, 2 sweeps
constexpr int CLS_BLOCKS = 2500;
constexpr int CLS_WAVES  = CLS_BLOCKS * 4;  // 10000; 2 items/wave = 20000 exact
constexpr int CL_BLOCKS  = 500;             // 2000 pairs, 1/wave exact

typedef __attribute__((ext_vector_type(4))) float f32x4;

__device__ __forceinline__ float wredsum(float v) {
    v += __shfl_xor(v, 1);  v += __shfl_xor(v, 2);  v += __shfl_xor(v, 4);
    v += __shfl_xor(v, 8);  v += __shfl_xor(v, 16); v += __shfl_xor(v, 32);
    return v;
}
__device__ __forceinline__ void wredsum2(float& a, float& b) {
    a += __shfl_xor(a, 1);  b += __shfl_xor(b, 1);
    a += __shfl_xor(a, 2);  b += __shfl_xor(b, 2);
    a += __shfl_xor(a, 4);  b += __shfl_xor(b, 4);
    a += __shfl_xor(a, 8);  b += __shfl_xor(b, 8);
    a += __shfl_xor(a, 16); b += __shfl_xor(b, 16);
    a += __shfl_xor(a, 32); b += __shfl_xor(b, 32);
}
__device__ __forceinline__ void wredsum4(float& a, float& b, float& c, float& d) {
    a += __shfl_xor(a, 1);  b += __shfl_xor(b, 1);
    c += __shfl_xor(c, 1);  d += __shfl_xor(d, 1);
    a += __shfl_xor(a, 2);  b += __shfl_xor(b, 2);
    c += __shfl_xor(c, 2);  d += __shfl_xor(d, 2);
    a += __shfl_xor(a, 4);  b += __shfl_xor(b, 4);
    c += __shfl_xor(c, 4);  d += __shfl_xor(d, 4);
    a += __shfl_xor(a, 8);  b += __shfl_xor(b, 8);
    c += __shfl_xor(c, 8);  d += __shfl_xor(d, 8);
    a += __shfl_xor(a, 16); b += __shfl_xor(b, 16);
    c += __shfl_xor(c, 16); d += __shfl_xor(d, 16);
    a += __shfl_xor(a, 32); b += __shfl_xor(b, 32);
    c += __shfl_xor(c, 32); d += __shfl_xor(d, 32);
}
__device__ __forceinline__ float wredmax(float v) {
    v = fmaxf(v, __shfl_xor(v, 1));  v = fmaxf(v, __shfl_xor(v, 2));
    v = fmaxf(v, __shfl_xor(v, 4));  v = fmaxf(v, __shfl_xor(v, 8));
    v = fmaxf(v, __shfl_xor(v, 16)); v = fmaxf(v, __shfl_xor(v, 32));
    return v;
}
__device__ __forceinline__ float bcast(float v, int l) {
    return __int_as_float(__builtin_amdgcn_readlane(__float_as_int(v), l));
}
__device__ __forceinline__ float fsq(float x)  { return __builtin_amdgcn_sqrtf(x); }
__device__ __forceinline__ float frc(float x)  { return __builtin_amdgcn_rcpf(x); }
__device__ __forceinline__ float artanh_fast(float n) {
    n = fminf(n, MAXNORM);
    return 0.5f * __logf((1.f + n) * frc(1.f - n));
}
__device__ __forceinline__ float acosh_fast(float z) {
    z = fmaxf(z, 1.0f + EPS1);
    return __logf(z + fsq(fmaf(z, z, -1.0f)));
}
__device__ __forceinline__ float tanh_fast(float x) {
    const float t = __expf(2.f * x);
    return (t - 1.f) * frc(t + 1.f);
}
__device__ __forceinline__ float dot4(const f32x4& a, const f32x4& b) {
    return (a.x * b.x + a.y * b.y) + (a.z * b.z + a.w * b.w);
}

__global__ __launch_bounds__(256) void fused_kernel(
        const float* __restrict__ emb,  const int* __restrict__ tri,
        const float* __restrict__ vtg,  const float* __restrict__ etag,
        const float* __restrict__ linw, const float* __restrict__ linb,
        const float* __restrict__ tw,   const int* __restrict__ labels,
        const int* __restrict__ imp,    float* __restrict__ part) {
    __shared__ float SA[64 * 65];   // cls: W^T then BT; cl: emb_tag^T
    __shared__ float XS[4 * 128];   // cls: per-wave 2x64 strip
    __shared__ float s64v[64];
    __shared__ float red4[4];
    const int tid  = threadIdx.x;
    const int lane = tid & 63, wid = tid >> 6;
    const int b    = blockIdx.x;
    float wsum = 0.f;

    // phase 0/1 loop: even blocks do [rank, other], odd do [other, rank]
    #pragma unroll 1
    for (int phase = 0; phase < 2; ++phase) {
        const bool rank_now = ((phase ^ (b & 1)) == 0);
        if (rank_now) {
            // ===== rank: 8 lanes/row, 8 rows/wave, 2 sweeps; anchored
            // 20-load clusters keep ~20 loads in flight per wave ====
            const int gw  = b * 4 + wid;
            const int sub = lane & 7;
            const int rw  = lane >> 3;
            const int dof = sub * 8;
            const bool o0 = sub & 1;
            const bool o1 = (sub >> 1) & 1;
            const bool o2 = (sub >> 2) & 1;
            float racc = 0.f;

            const int  row0 = gw * 8 + rw;
            const int* t0 = tri + (long)row0 * 10;
            const int* t1 = t0 + (long)(RANK_WAVES * 8) * 10;
            const int2 a01 = *reinterpret_cast<const int2*>(t0);
            const int2 a23 = *reinterpret_cast<const int2*>(t0 + 2);
            const int2 a45 = *reinterpret_cast<const int2*>(t0 + 4);
            const int2 a67 = *reinterpret_cast<const int2*>(t0 + 6);
            const int2 a89 = *reinterpret_cast<const int2*>(t0 + 8);
            const int2 b01 = *reinterpret_cast<const int2*>(t1);
            const int2 b23 = *reinterpret_cast<const int2*>(t1 + 2);
            const int2 b45 = *reinterpret_cast<const int2*>(t1 + 4);
            const int2 b67 = *reinterpret_cast<const int2*>(t1 + 6);
            const int2 b89 = *reinterpret_cast<const int2*>(t1 + 8);

            auto ldvec = [&](int idx, f32x4& lo, f32x4& hi) {
                const float* q = emb + (long)idx * 64 + dof;
                lo = *reinterpret_cast<const f32x4*>(q);
                hi = *reinterpret_cast<const f32x4*>(q + 4);
            };
            auto finish = [&](float e0, float e1, float e2, float e3,
                              float e4, float e5, float e6, float e7,
                              float ps, float alpha) {
                float s_;
                s_ = o0 ? e0 : e1; s_ = __shfl_xor(s_, 1); const float f0 = (o0 ? e1 : e0) + s_;
                s_ = o0 ? e2 : e3; s_ = __shfl_xor(s_, 1); const float f1 = (o0 ? e3 : e2) + s_;
                s_ = o0 ? e4 : e5; s_ = __shfl_xor(s_, 1); const float f2 = (o0 ? e5 : e4) + s_;
                s_ = o0 ? e6 : e7; s_ = __shfl_xor(s_, 1); const float f3 = (o0 ? e7 : e6) + s_;
                s_ = o1 ? f0 : f1; s_ = __shfl_xor(s_, 2); const float g0 = (o1 ? f1 : f0) + s_;
                s_ = o1 ? f2 : f3; s_ = __shfl_xor(s_, 2); const float g1 = (o1 ? f3 : f2) + s_;
                s_ = o2 ? g0 : g1; s_ = __shfl_xor(s_, 4); const float dn = (o2 ? g1 : g0) + s_;
                const float dneg = acosh_fast(-dn);
                racc += alpha * fmaxf(ps - dneg * dneg + MARGIN2, 0.f);
            };

            // ======== sweep 0: 20 loads, volatile-asm anchored ========
            f32x4 ua0, ub0, pa0, pb0;
            f32x4 na0,nb0, na1,nb1, na2,nb2, na3,nb3, na4,nb4, na5,nb5, na6,nb6, na7,nb7;
            ldvec(a01.x, ua0, ub0);  ldvec(a01.y, pa0, pb0);
            ldvec(a23.x, na0, nb0);  ldvec(a23.y, na1, nb1);
            ldvec(a45.x, na2, nb2);  ldvec(a45.y, na3, nb3);
            ldvec(a67.x, na4, nb4);  ldvec(a67.y, na5, nb5);
            ldvec(a89.x, na6, nb6);  ldvec(a89.y, na7, nb7);
            asm volatile(""
                : "+v"(ua0), "+v"(ub0), "+v"(pa0), "+v"(pb0),
                  "+v"(na0), "+v"(nb0), "+v"(na1), "+v"(nb1),
                  "+v"(na2), "+v"(nb2), "+v"(na3), "+v"(nb3),
                  "+v"(na4), "+v"(nb4), "+v"(na5), "+v"(nb5),
                  "+v"(na6), "+v"(nb6), "+v"(na7), "+v"(nb7));

            const float u00  = ua0.x;                    // dim0 (real on sub==0)
            const float u0b0 = __shfl(u00, lane & 56);   // row-base lane's dim0
            if (sub == 0) ua0.x = -ua0.x;                // fold lorentz sign
            float dp0 = dot4(ua0, pa0) + dot4(ub0, pb0);
            dp0 += __shfl_xor(dp0, 1); dp0 += __shfl_xor(dp0, 2); dp0 += __shfl_xor(dp0, 4);
            const float dpos0  = acosh_fast(-dp0);
            const float ps0    = dpos0 * dpos0;
            const float alpha0 = acosh_fast(u0b0);
            const float e0 = dot4(ua0, na0) + dot4(ub0, nb0);
            const float e1 = dot4(ua0, na1) + dot4(ub0, nb1);
            const float e2 = dot4(ua0, na2) + dot4(ub0, nb2);
            const float e3 = dot4(ua0, na3) + dot4(ub0, nb3);
            const float e4 = dot4(ua0, na4) + dot4(ub0, nb4);
            const float e5 = dot4(ua0, na5) + dot4(ub0, nb5);
            const float e6 = dot4(ua0, na6) + dot4(ub0, nb6);
            const float e7 = dot4(ua0, na7) + dot4(ub0, nb7);
            finish(e0, e1, e2, e3, e4, e5, e6, e7, ps0, alpha0);

            // ======== sweep 1: 20 loads, anchored ========
            f32x4 ua1, ub1, pa1, pb1;
            f32x4 qa0,qb0, qa1,qb1, qa2,qb2, qa3,qb3, qa4,qb4, qa5,qb5, qa6,qb6, qa7,qb7;
            ldvec(b01.x, ua1, ub1);  ldvec(b01.y, pa1, pb1);
            ldvec(b23.x, qa0, qb0);  ldvec(b23.y, qa1, qb1);
            ldvec(b45.x, qa2, qb2);  ldvec(b45.y, qa3, qb3);
            ldvec(b67.x, qa4, qb4);  ldvec(b67.y, qa5, qb5);
            ldvec(b89.x, qa6, qb6);  ldvec(b89.y, qa7, qb7);
            asm volatile(""
                : "+v"(ua1), "+v"(ub1), "+v"(pa1), "+v"(pb1),
                  "+v"(qa0), "+v"(qb0), "+v"(qa1), "+v"(qb1),
                  "+v"(qa2), "+v"(qb2), "+v"(qa3), "+v"(qb3),
                  "+v"(qa4), "+v"(qb4), "+v"(qa5), "+v"(qb5),
                  "+v"(qa6), "+v"(qb6), "+v"(qa7), "+v"(qb7));

            const float u01  = ua1.x;
            const float u0b1 = __shfl(u01, lane & 56);
            if (sub == 0) ua1.x = -ua1.x;
            float dp1 = dot4(ua1, pa1) + dot4(ub1, pb1);
            dp1 += __shfl_xor(dp1, 1); dp1 += __shfl_xor(dp1, 2); dp1 += __shfl_xor(dp1, 4);
            const float dpos1  = acosh_fast(-dp1);
            const float ps1    = dpos1 * dpos1;
            const float alpha1 = acosh_fast(u0b1);
            const float h0 = dot4(ua1, qa0) + dot4(ub1, qb0);
            const float h1 = dot4(ua1, qa1) + dot4(ub1, qb1);
            const float h2 = dot4(ua1, qa2) + dot4(ub1, qb2);
            const float h3 = dot4(ua1, qa3) + dot4(ub1, qb3);
            const float h4 = dot4(ua1, qa4) + dot4(ub1, qb4);
            const float h5 = dot4(ua1, qa5) + dot4(ub1, qb5);
            const float h6 = dot4(ua1, qa6) + dot4(ub1, qb6);
            const float h7 = dot4(ua1, qa7) + dot4(ub1, qb7);
            finish(h0, h1, h2, h3, h4, h5, h6, h7, ps1, alpha1);

            wsum += wredsum(racc);
        } else if (b < CLS_BLOCKS) {
            // ================= cls: 2 items/wave, LDS-broadcast =============
            const int gw = b * 4 + wid;                // 0..9999
            const int i0 = gw, i1 = gw + CLS_WAVES;    // both always valid
            const int xb = wid * 128;

            for (int i = tid; i < 4096; i += 256) {
                SA[(i & 63) * 65 + (i >> 6)] = linw[i];    // W transposed
            }
            __syncthreads();
            const float bias = linb[lane];
            const float y2b  = wredsum(bias * bias);

            float xv0 = vtg[(long)i0 * 64 + lane];
            float xv1 = vtg[(long)i1 * 64 + lane];
            float n20 = xv0 * xv0, n21 = xv1 * xv1;
            wredsum2(n20, n21);
            float xn0 = fsq(fmaxf(n20, 1e-15f)), xn1 = fsq(fmaxf(n21, 1e-15f));
            if (xn0 > MAXNORM) { xv0 *= MAXNORM * frc(xn0); float t = wredsum(xv0 * xv0); xn0 = fsq(fmaxf(t, 1e-15f)); }
            if (xn1 > MAXNORM) { xv1 *= MAXNORM * frc(xn1); float t = wredsum(xv1 * xv1); xn1 = fsq(fmaxf(t, 1e-15f)); }

            XS[xb + lane]      = xv0;
            XS[xb + 64 + lane] = xv1;
            float ma0 = 0.f, ma1 = 0.f, mb0 = 0.f, mb1 = 0.f;
            #pragma unroll
            for (int d = 0; d < 64; d += 2) {
                const float w0 = SA[(d)     * 65 + lane];
                const float w1 = SA[(d + 1) * 65 + lane];
                const float xA0 = XS[xb + d],      xA1 = XS[xb + d + 1];
                const float xB0 = XS[xb + 64 + d], xB1 = XS[xb + 64 + d + 1];
                ma0 = fmaf(xA0, w0, ma0);  ma1 = fmaf(xA1, w1, ma1);
                mb0 = fmaf(xB0, w0, mb0);  mb1 = fmaf(xB1, w1, mb1);
            }
            const float mxA = ma0 + ma1, mxB = mb0 + mb1;

            float mnA2 = mxA * mxA, mnB2 = mxB * mxB;
            wredsum2(mnA2, mnB2);
            const float mnA = fsq(fmaxf(mnA2, 1e-15f)), mnB = fsq(fmaxf(mnB2, 1e-15f));
            const float gA = tanh_fast(mnA * frc(xn0) * artanh_fast(xn0));
            const float gB = tanh_fast(mnB * frc(xn1) * artanh_fast(xn1));
            const float hA = gA * frc(mnA) * mxA, hB = gB * frc(mnB) * mxB;
            float x2hA = hA * hA, xyA = hA * bias, x2hB = hB * hB, xyB = hB * bias;
            wredsum4(x2hA, xyA, x2hB, xyB);
            const float AA  = 1.f + 2.f * xyA + y2b, AB = 1.f + 2.f * xyB + y2b;
            const float BcA = 1.f - x2hA,            BcB = 1.f - x2hB;
            const float denA = fmaxf(1.f + 2.f * xyA + x2hA * y2b, 1e-15f);
            const float denB = fmaxf(1.f + 2.f * xyB + x2hB * y2b, 1e-15f);
            float hhA = (AA * hA + BcA * bias) * frc(denA);
            float hhB = (AB * hB + BcB * bias) * frc(denB);
            float h2A = hhA * hhA, h2B = hhB * hhB;
            wredsum2(h2A, h2B);
            float hnA = fsq(fmaxf(h2A, 1e-15f)), hnB = fsq(fmaxf(h2B, 1e-15f));
            if (hnA > MAXNORM) { hhA *= MAXNORM * frc(hnA); float t = wredsum(hhA * hhA); hnA = fsq(fmaxf(t, 1e-15f)); }
            if (hnB > MAXNORM) { hhB *= MAXNORM * frc(hnB); float t = wredsum(hhB * hhB); hnB = fsq(fmaxf(t, 1e-15f)); }
            const float aA = artanh_fast(hnA) * frc(hnA) * hhA;   // ball_logmap0
            const float aB = artanh_fast(hnB) * frc(hnB) * hhB;

            XS[xb + lane]      = aA;
            XS[xb + 64 + lane] = aB;
            __syncthreads();
            {   // rebuild SA: BT = logmap0(emb_tag)^T, s64v = ||bt||^2
                const int j = tid >> 2, p = tid & 3;
                float e[16]; float s2 = 0.f;
                #pragma unroll
                for (int m = 0; m < 16; ++m) { e[m] = etag[j * 64 + p * 16 + m]; s2 += e[m] * e[m]; }
                s2 += __shfl_xor(s2, 1); s2 += __shfl_xor(s2, 2);
                const float n  = fsq(fmaxf(s2, 1e-15f));
                const float sc = artanh_fast(n) * frc(n);
                #pragma unroll
                for (int m = 0; m < 16; ++m) SA[(p * 16 + m) * 65 + j] = sc * e[m];
                if (p == 0) s64v[j] = sc * sc * s2;
            }
            __syncthreads();

            float da0 = 0.f, da1 = 0.f, db0 = 0.f, db1 = 0.f;
            #pragma unroll
            for (int d = 0; d < 64; d += 2) {
                const float w0 = SA[(d)     * 65 + lane];
                const float w1 = SA[(d + 1) * 65 + lane];
                const float xA0 = XS[xb + d],      xA1 = XS[xb + d + 1];
                const float xB0 = XS[xb + 64 + d], xB1 = XS[xb + 64 + d + 1];
                da0 = fmaf(xA0, w0, da0);  da1 = fmaf(xA1, w1, da1);
                db0 = fmaf(xB0, w0, db0);  db1 = fmaf(xB1, w1, db1);
            }
            float a2A = aA * aA, a2B = aB * aB;
            wredsum2(a2A, a2B);
            const float b2l = s64v[lane];
            const float twl = tw[lane];
            const float distA = fsq(fmaxf(a2A + b2l - 2.f * (da0 + da1), 1e-12f));
            const float distB = fsq(fmaxf(a2B + b2l - 2.f * (db0 + db1), 1e-12f));
            const float lpA = __logf(distA) - twl;
            const float lpB = __logf(distB) - twl;

            XS[xb + lane]      = lpA;
            XS[xb + 64 + lane] = lpB;
            const float qA = lpA + MARGIN1, qB = lpB + MARGIN1;
            float s00 = 0.f, s01 = 0.f, s10 = 0.f, s11 = 0.f;
            #pragma unroll
            for (int k = 0; k < 64; k += 2) {
                const float lA0 = XS[xb + k],      lA1 = XS[xb + k + 1];
                const float lB0 = XS[xb + 64 + k], lB1 = XS[xb + 64 + k + 1];
                s00 += fmaxf(qA - lA0, 0.f);  s01 += fmaxf(qA - lA1, 0.f);
                s10 += fmaxf(qB - lB0, 0.f);  s11 += fmaxf(qB - lB1, 0.f);
            }
            const float hsA = s00 + s01, hsB = s10 + s11;
            const float cA = (labels[(long)i0 * 64 + lane] > 0) ? hsA : 0.f;
            const float cB = (labels[(long)i1 * 64 + lane] > 0) ? hsB : 0.f;
            wsum += wredsum(cA + cB);
        } else if (b < CLS_BLOCKS + CL_BLOCKS) {
            // ================= cl: 1 pair/wave =================
            const int gw = (b - CLS_BLOCKS) * 4 + wid;   // 0..1999 exact
            {
                const int j = tid >> 2, p = tid & 3;
                float s2 = 0.f;
                #pragma unroll
                for (int m = 0; m < 16; ++m) {
                    const float e = etag[j * 64 + p * 16 + m];
                    s2 += e * e;
                    SA[(p * 16 + m) * 65 + j] = e;
                }
                s2 += __shfl_xor(s2, 1); s2 += __shfl_xor(s2, 2);
                if (p == 0) s64v[j] = s2;
            }
            __syncthreads();
            const int ai = imp[gw * 2];
            const int bi = imp[gw * 2 + 1];
            const float y2l = s64v[lane];
            const float x2  = s64v[ai];
            float c0 = 0.f, c1 = 0.f, c2 = 0.f, c3 = 0.f;
            #pragma unroll
            for (int d = 0; d < 64; d += 4) {
                c0 = fmaf(SA[(d)     * 65 + ai], SA[(d)     * 65 + lane], c0);
                c1 = fmaf(SA[(d + 1) * 65 + ai], SA[(d + 1) * 65 + lane], c1);
                c2 = fmaf(SA[(d + 2) * 65 + ai], SA[(d + 2) * 65 + lane], c2);
                c3 = fmaf(SA[(d + 3) * 65 + ai], SA[(d + 3) * 65 + lane], c3);
            }
            const float c   = (c0 + c1) + (c2 + c3);
            const float A   = 1.f - 2.f * c + y2l;
            const float Bc  = 1.f - x2;
            const float nn  = A * A * x2 - 2.f * A * Bc * c + Bc * Bc * y2l;
            const float den = fmaxf(1.f - 2.f * c + x2 * y2l, 1e-15f);
            float n = fsq(fmaxf(nn * frc(den * den), 1e-15f));
            n = fminf(n, MAXNORM);
            const float dd = __logf((1.f + n) * frc(1.f - n));   // 2*artanh(n)
            float dist = dd * dd;
            if (lane == ai) dist = 0.f;    // self-distance: ref < 1e-9 -> masked
            const float logit = (dist > 1e-9f) ? (-dist * (1.f / TAU)) : -1e30f;
            const float dp = bcast(dist, bi);
            const float lp = bcast(logit, bi);
            const float m  = wredmax(logit);
            const float se = wredsum(__expf(logit - m)) + __expf(lp - m);
            wsum += m + __logf(se) + dp * (1.f / TAU);
        }
        __syncthreads();   // phase boundary (LDS role switch)
    }

    if (lane == 0) red4[wid] = wsum;
    __syncthreads();
    if (tid == 0) part[b] = red4[0] + red4[1] + red4[2] + red4[3];
}

__global__ __launch_bounds__(256) void final_reduce(
        const float* __restrict__ parts, int n, float* __restrict__ out) {
    __shared__ double red[256];
    double s = 0.0;
    for (int i = threadIdx.x; i < n; i += 256) s += (double)parts[i];
    red[threadIdx.x] = s;
    __syncthreads();
    for (int off = 128; off > 0; off >>= 1) {
        if (threadIdx.x < off) red[threadIdx.x] += red[threadIdx.x + off];
        __syncthreads();
    }
    if (threadIdx.x == 0) out[0] = (float)red[0];
}

} // namespace

extern "C" void kernel_launch(void* const* d_in, const int* in_sizes, int n_in,
                              void* d_out, int out_size, void* d_ws, size_t ws_size,
                              hipStream_t stream) {
    const float* emb    = (const float*)d_in[0];
    const float* vtg    = (const float*)d_in[1];
    const float* etag   = (const float*)d_in[2];
    const float* linw   = (const float*)d_in[3];
    const float* linb   = (const float*)d_in[4];
    const float* tw     = (const float*)d_in[5];
    const int*   tri    = (const int*)d_in[6];
    const int*   labels = (const int*)d_in[7];
    const int*   imp    = (const int*)d_in[8];
    float* parts = (float*)d_ws;

    fused_kernel<<<NBLK, 256, 0, stream>>>(emb, tri, vtg, etag, linw, linb,
                                           tw, labels, imp, parts);
    final_reduce<<<1, 256, 0, stream>>>(parts, NBLK, (float*)d_out);
}

// Round 19
// 71.868 us; speedup vs baseline: 1.3101x; 1.3101x over previous
//
#include <hip/hip_runtime.h>
#include <math.h>

namespace {

constexpr int NUM_NEG   = 8;
constexpr int BROWS     = 262144;
constexpr float MARGIN1 = 0.1f;
constexpr float MARGIN2 = 0.1f;
constexpr float TAU     = 0.2f;
constexpr float EPS1    = 1e-7f;
constexpr float MAXNORM = 1.0f - 1e-5f;

// Bresenham-interleaved roles: rank/cls/cl blocks evenly mixed so they
// co-reside on CUs (rank = latency-bound, cls = compute-bound -> overlap).
constexpr int RANK_BLOCKS = 4096;
constexpr int RANK_WAVES  = RANK_BLOCKS * 4;   // 16384; 8 rows/wave, 2 sweeps
constexpr int CLS_BLOCKS  = 2500;
constexpr int CLS_WAVES   = CLS_BLOCKS * 4;    // 10000; 2 items/wave = 20000 exact
constexpr int CL_BLOCKS   = 500;               // 2000 pairs, 1/wave exact
constexpr int NBLK = RANK_BLOCKS + CLS_BLOCKS + CL_BLOCKS;   // 7096

typedef __attribute__((ext_vector_type(4))) float f32x4;

__device__ __forceinline__ float wredsum(float v) {
    v += __shfl_xor(v, 1);  v += __shfl_xor(v, 2);  v += __shfl_xor(v, 4);
    v += __shfl_xor(v, 8);  v += __shfl_xor(v, 16); v += __shfl_xor(v, 32);
    return v;
}
__device__ __forceinline__ void wredsum2(float& a, float& b) {
    a += __shfl_xor(a, 1);  b += __shfl_xor(b, 1);
    a += __shfl_xor(a, 2);  b += __shfl_xor(b, 2);
    a += __shfl_xor(a, 4);  b += __shfl_xor(b, 4);
    a += __shfl_xor(a, 8);  b += __shfl_xor(b, 8);
    a += __shfl_xor(a, 16); b += __shfl_xor(b, 16);
    a += __shfl_xor(a, 32); b += __shfl_xor(b, 32);
}
__device__ __forceinline__ void wredsum4(float& a, float& b, float& c, float& d) {
    a += __shfl_xor(a, 1);  b += __shfl_xor(b, 1);
    c += __shfl_xor(c, 1);  d += __shfl_xor(d, 1);
    a += __shfl_xor(a, 2);  b += __shfl_xor(b, 2);
    c += __shfl_xor(c, 2);  d += __shfl_xor(d, 2);
    a += __shfl_xor(a, 4);  b += __shfl_xor(b, 4);
    c += __shfl_xor(c, 4);  d += __shfl_xor(d, 4);
    a += __shfl_xor(a, 8);  b += __shfl_xor(b, 8);
    c += __shfl_xor(c, 8);  d += __shfl_xor(d, 8);
    a += __shfl_xor(a, 16); b += __shfl_xor(b, 16);
    c += __shfl_xor(c, 16); d += __shfl_xor(d, 16);
    a += __shfl_xor(a, 32); b += __shfl_xor(b, 32);
    c += __shfl_xor(c, 32); d += __shfl_xor(d, 32);
}
__device__ __forceinline__ float wredmax(float v) {
    v = fmaxf(v, __shfl_xor(v, 1));  v = fmaxf(v, __shfl_xor(v, 2));
    v = fmaxf(v, __shfl_xor(v, 4));  v = fmaxf(v, __shfl_xor(v, 8));
    v = fmaxf(v, __shfl_xor(v, 16)); v = fmaxf(v, __shfl_xor(v, 32));
    return v;
}
__device__ __forceinline__ float bcast(float v, int l) {
    return __int_as_float(__builtin_amdgcn_readlane(__float_as_int(v), l));
}
__device__ __forceinline__ float fsq(float x)  { return __builtin_amdgcn_sqrtf(x); }
__device__ __forceinline__ float frc(float x)  { return __builtin_amdgcn_rcpf(x); }
__device__ __forceinline__ float artanh_fast(float n) {
    n = fminf(n, MAXNORM);
    return 0.5f * __logf((1.f + n) * frc(1.f - n));
}
__device__ __forceinline__ float acosh_fast(float z) {
    z = fmaxf(z, 1.0f + EPS1);
    return __logf(z + fsq(fmaf(z, z, -1.0f)));
}
__device__ __forceinline__ float tanh_fast(float x) {
    const float t = __expf(2.f * x);
    return (t - 1.f) * frc(t + 1.f);
}
__device__ __forceinline__ float dot4(const f32x4& a, const f32x4& b) {
    return (a.x * b.x + a.y * b.y) + (a.z * b.z + a.w * b.w);
}

__global__ __launch_bounds__(256) void fused_kernel(
        const float* __restrict__ emb,  const int* __restrict__ tri,
        const float* __restrict__ vtg,  const float* __restrict__ etag,
        const float* __restrict__ linw, const float* __restrict__ linb,
        const float* __restrict__ tw,   const int* __restrict__ labels,
        const int* __restrict__ imp,    float* __restrict__ part) {
    __shared__ float SA[64 * 65];   // cls: W^T then BT; cl: emb_tag^T
    __shared__ float XS[4 * 128];   // cls: per-wave 2x64 strip
    __shared__ float s64v[64];
    __shared__ float red4[4];
    const int tid  = threadIdx.x;
    const int lane = tid & 63, wid = tid >> 6;
    const int b    = blockIdx.x;
    float wsum = 0.f;

    // Bresenham role assignment: exactly RANK_BLOCKS rank blocks, evenly
    // interleaved; rank_id = rb is a bijection onto [0, RANK_BLOCKS).
    const int rb  = (int)(((long)b       * RANK_BLOCKS) / NBLK);
    const int rb1 = (int)(((long)(b + 1) * RANK_BLOCKS) / NBLK);
    const bool is_rank = (rb1 > rb);
    const int  o = b - rb;                 // non-rank appearance index

    if (is_rank) {
        // ===== rank: 8 lanes/row, 8 rows/wave, 2 sweeps; anchored 20-load
        // clusters keep ~20 loads in flight per wave ====
        const int gw  = rb * 4 + wid;
        const int sub = lane & 7;
        const int rw  = lane >> 3;
        const int dof = sub * 8;
        const bool o0 = sub & 1;
        const bool o1 = (sub >> 1) & 1;
        const bool o2 = (sub >> 2) & 1;
        float racc = 0.f;

        const int  row0 = gw * 8 + rw;
        const int* t0 = tri + (long)row0 * 10;
        const int* t1 = t0 + (long)(RANK_WAVES * 8) * 10;
        const int2 a01 = *reinterpret_cast<const int2*>(t0);
        const int2 a23 = *reinterpret_cast<const int2*>(t0 + 2);
        const int2 a45 = *reinterpret_cast<const int2*>(t0 + 4);
        const int2 a67 = *reinterpret_cast<const int2*>(t0 + 6);
        const int2 a89 = *reinterpret_cast<const int2*>(t0 + 8);
        const int2 b01 = *reinterpret_cast<const int2*>(t1);
        const int2 b23 = *reinterpret_cast<const int2*>(t1 + 2);
        const int2 b45 = *reinterpret_cast<const int2*>(t1 + 4);
        const int2 b67 = *reinterpret_cast<const int2*>(t1 + 6);
        const int2 b89 = *reinterpret_cast<const int2*>(t1 + 8);

        auto ldvec = [&](int idx, f32x4& lo, f32x4& hi) {
            const float* q = emb + (long)idx * 64 + dof;
            lo = *reinterpret_cast<const f32x4*>(q);
            hi = *reinterpret_cast<const f32x4*>(q + 4);
        };
        auto finish = [&](float e0, float e1, float e2, float e3,
                          float e4, float e5, float e6, float e7,
                          float ps, float alpha) {
            float s_;
            s_ = o0 ? e0 : e1; s_ = __shfl_xor(s_, 1); const float f0 = (o0 ? e1 : e0) + s_;
            s_ = o0 ? e2 : e3; s_ = __shfl_xor(s_, 1); const float f1 = (o0 ? e3 : e2) + s_;
            s_ = o0 ? e4 : e5; s_ = __shfl_xor(s_, 1); const float f2 = (o0 ? e5 : e4) + s_;
            s_ = o0 ? e6 : e7; s_ = __shfl_xor(s_, 1); const float f3 = (o0 ? e7 : e6) + s_;
            s_ = o1 ? f0 : f1; s_ = __shfl_xor(s_, 2); const float g0 = (o1 ? f1 : f0) + s_;
            s_ = o1 ? f2 : f3; s_ = __shfl_xor(s_, 2); const float g1 = (o1 ? f3 : f2) + s_;
            s_ = o2 ? g0 : g1; s_ = __shfl_xor(s_, 4); const float dn = (o2 ? g1 : g0) + s_;
            const float dneg = acosh_fast(-dn);
            racc += alpha * fmaxf(ps - dneg * dneg + MARGIN2, 0.f);
        };

        // ======== sweep 0: 20 loads, volatile-asm anchored ========
        f32x4 ua0, ub0, pa0, pb0;
        f32x4 na0,nb0, na1,nb1, na2,nb2, na3,nb3, na4,nb4, na5,nb5, na6,nb6, na7,nb7;
        ldvec(a01.x, ua0, ub0);  ldvec(a01.y, pa0, pb0);
        ldvec(a23.x, na0, nb0);  ldvec(a23.y, na1, nb1);
        ldvec(a45.x, na2, nb2);  ldvec(a45.y, na3, nb3);
        ldvec(a67.x, na4, nb4);  ldvec(a67.y, na5, nb5);
        ldvec(a89.x, na6, nb6);  ldvec(a89.y, na7, nb7);
        asm volatile(""
            : "+v"(ua0), "+v"(ub0), "+v"(pa0), "+v"(pb0),
              "+v"(na0), "+v"(nb0), "+v"(na1), "+v"(nb1),
              "+v"(na2), "+v"(nb2), "+v"(na3), "+v"(nb3),
              "+v"(na4), "+v"(nb4), "+v"(na5), "+v"(nb5),
              "+v"(na6), "+v"(nb6), "+v"(na7), "+v"(nb7));

        const float u00  = ua0.x;                    // dim0 (real on sub==0)
        const float u0b0 = __shfl(u00, lane & 56);   // row-base lane's dim0
        if (sub == 0) ua0.x = -ua0.x;                // fold lorentz sign into u
        float dp0 = dot4(ua0, pa0) + dot4(ub0, pb0);
        dp0 += __shfl_xor(dp0, 1); dp0 += __shfl_xor(dp0, 2); dp0 += __shfl_xor(dp0, 4);
        const float dpos0  = acosh_fast(-dp0);
        const float ps0    = dpos0 * dpos0;
        const float alpha0 = acosh_fast(u0b0);
        const float e0 = dot4(ua0, na0) + dot4(ub0, nb0);
        const float e1 = dot4(ua0, na1) + dot4(ub0, nb1);
        const float e2 = dot4(ua0, na2) + dot4(ub0, nb2);
        const float e3 = dot4(ua0, na3) + dot4(ub0, nb3);
        const float e4 = dot4(ua0, na4) + dot4(ub0, nb4);
        const float e5 = dot4(ua0, na5) + dot4(ub0, nb5);
        const float e6 = dot4(ua0, na6) + dot4(ub0, nb6);
        const float e7 = dot4(ua0, na7) + dot4(ub0, nb7);
        finish(e0, e1, e2, e3, e4, e5, e6, e7, ps0, alpha0);

        // ======== sweep 1: 20 loads, anchored ========
        f32x4 ua1, ub1, pa1, pb1;
        f32x4 qa0,qb0, qa1,qb1, qa2,qb2, qa3,qb3, qa4,qb4, qa5,qb5, qa6,qb6, qa7,qb7;
        ldvec(b01.x, ua1, ub1);  ldvec(b01.y, pa1, pb1);
        ldvec(b23.x, qa0, qb0);  ldvec(b23.y, qa1, qb1);
        ldvec(b45.x, qa2, qb2);  ldvec(b45.y, qa3, qb3);
        ldvec(b67.x, qa4, qb4);  ldvec(b67.y, qa5, qb5);
        ldvec(b89.x, qa6, qb6);  ldvec(b89.y, qa7, qb7);
        asm volatile(""
            : "+v"(ua1), "+v"(ub1), "+v"(pa1), "+v"(pb1),
              "+v"(qa0), "+v"(qb0), "+v"(qa1), "+v"(qb1),
              "+v"(qa2), "+v"(qb2), "+v"(qa3), "+v"(qb3),
              "+v"(qa4), "+v"(qb4), "+v"(qa5), "+v"(qb5),
              "+v"(qa6), "+v"(qb6), "+v"(qa7), "+v"(qb7));

        const float u01  = ua1.x;
        const float u0b1 = __shfl(u01, lane & 56);
        if (sub == 0) ua1.x = -ua1.x;
        float dp1 = dot4(ua1, pa1) + dot4(ub1, pb1);
        dp1 += __shfl_xor(dp1, 1); dp1 += __shfl_xor(dp1, 2); dp1 += __shfl_xor(dp1, 4);
        const float dpos1  = acosh_fast(-dp1);
        const float ps1    = dpos1 * dpos1;
        const float alpha1 = acosh_fast(u0b1);
        const float h0 = dot4(ua1, qa0) + dot4(ub1, qb0);
        const float h1 = dot4(ua1, qa1) + dot4(ub1, qb1);
        const float h2 = dot4(ua1, qa2) + dot4(ub1, qb2);
        const float h3 = dot4(ua1, qa3) + dot4(ub1, qb3);
        const float h4 = dot4(ua1, qa4) + dot4(ub1, qb4);
        const float h5 = dot4(ua1, qa5) + dot4(ub1, qb5);
        const float h6 = dot4(ua1, qa6) + dot4(ub1, qb6);
        const float h7 = dot4(ua1, qa7) + dot4(ub1, qb7);
        finish(h0, h1, h2, h3, h4, h5, h6, h7, ps1, alpha1);

        wsum = wredsum(racc);
    } else if (o < CLS_BLOCKS) {
        // ================= cls: 2 items/wave, LDS-broadcast =================
        const int gw = o * 4 + wid;                // 0..9999
        const int i0 = gw, i1 = gw + CLS_WAVES;    // both always valid
        const int xb = wid * 128;

        for (int i = tid; i < 4096; i += 256) {
            SA[(i & 63) * 65 + (i >> 6)] = linw[i];    // W transposed
        }
        __syncthreads();
        const float bias = linb[lane];
        const float y2b  = wredsum(bias * bias);

        float xv0 = vtg[(long)i0 * 64 + lane];
        float xv1 = vtg[(long)i1 * 64 + lane];
        float n20 = xv0 * xv0, n21 = xv1 * xv1;
        wredsum2(n20, n21);
        float xn0 = fsq(fmaxf(n20, 1e-15f)), xn1 = fsq(fmaxf(n21, 1e-15f));
        if (xn0 > MAXNORM) { xv0 *= MAXNORM * frc(xn0); float t = wredsum(xv0 * xv0); xn0 = fsq(fmaxf(t, 1e-15f)); }
        if (xn1 > MAXNORM) { xv1 *= MAXNORM * frc(xn1); float t = wredsum(xv1 * xv1); xn1 = fsq(fmaxf(t, 1e-15f)); }

        XS[xb + lane]      = xv0;
        XS[xb + 64 + lane] = xv1;
        float ma0 = 0.f, ma1 = 0.f, mb0 = 0.f, mb1 = 0.f;
        #pragma unroll
        for (int d = 0; d < 64; d += 2) {
            const float w0 = SA[(d)     * 65 + lane];
            const float w1 = SA[(d + 1) * 65 + lane];
            const float xA0 = XS[xb + d],      xA1 = XS[xb + d + 1];
            const float xB0 = XS[xb + 64 + d], xB1 = XS[xb + 64 + d + 1];
            ma0 = fmaf(xA0, w0, ma0);  ma1 = fmaf(xA1, w1, ma1);
            mb0 = fmaf(xB0, w0, mb0);  mb1 = fmaf(xB1, w1, mb1);
        }
        const float mxA = ma0 + ma1, mxB = mb0 + mb1;

        float mnA2 = mxA * mxA, mnB2 = mxB * mxB;
        wredsum2(mnA2, mnB2);
        const float mnA = fsq(fmaxf(mnA2, 1e-15f)), mnB = fsq(fmaxf(mnB2, 1e-15f));
        const float gA = tanh_fast(mnA * frc(xn0) * artanh_fast(xn0));
        const float gB = tanh_fast(mnB * frc(xn1) * artanh_fast(xn1));
        const float hA = gA * frc(mnA) * mxA, hB = gB * frc(mnB) * mxB;
        float x2hA = hA * hA, xyA = hA * bias, x2hB = hB * hB, xyB = hB * bias;
        wredsum4(x2hA, xyA, x2hB, xyB);
        const float AA  = 1.f + 2.f * xyA + y2b, AB = 1.f + 2.f * xyB + y2b;
        const float BcA = 1.f - x2hA,            BcB = 1.f - x2hB;
        const float denA = fmaxf(1.f + 2.f * xyA + x2hA * y2b, 1e-15f);
        const float denB = fmaxf(1.f + 2.f * xyB + x2hB * y2b, 1e-15f);
        float hhA = (AA * hA + BcA * bias) * frc(denA);
        float hhB = (AB * hB + BcB * bias) * frc(denB);
        float h2A = hhA * hhA, h2B = hhB * hhB;
        wredsum2(h2A, h2B);
        float hnA = fsq(fmaxf(h2A, 1e-15f)), hnB = fsq(fmaxf(h2B, 1e-15f));
        if (hnA > MAXNORM) { hhA *= MAXNORM * frc(hnA); float t = wredsum(hhA * hhA); hnA = fsq(fmaxf(t, 1e-15f)); }
        if (hnB > MAXNORM) { hhB *= MAXNORM * frc(hnB); float t = wredsum(hhB * hhB); hnB = fsq(fmaxf(t, 1e-15f)); }
        const float aA = artanh_fast(hnA) * frc(hnA) * hhA;   // ball_logmap0
        const float aB = artanh_fast(hnB) * frc(hnB) * hhB;

        XS[xb + lane]      = aA;
        XS[xb + 64 + lane] = aB;
        __syncthreads();
        {   // rebuild SA: BT = logmap0(emb_tag)^T, s64v = ||bt||^2
            const int j = tid >> 2, p = tid & 3;
            float e[16]; float s2 = 0.f;
            #pragma unroll
            for (int m = 0; m < 16; ++m) { e[m] = etag[j * 64 + p * 16 + m]; s2 += e[m] * e[m]; }
            s2 += __shfl_xor(s2, 1); s2 += __shfl_xor(s2, 2);
            const float n  = fsq(fmaxf(s2, 1e-15f));
            const float sc = artanh_fast(n) * frc(n);
            #pragma unroll
            for (int m = 0; m < 16; ++m) SA[(p * 16 + m) * 65 + j] = sc * e[m];
            if (p == 0) s64v[j] = sc * sc * s2;
        }
        __syncthreads();

        float da0 = 0.f, da1 = 0.f, db0 = 0.f, db1 = 0.f;
        #pragma unroll
        for (int d = 0; d < 64; d += 2) {
            const float w0 = SA[(d)     * 65 + lane];
            const float w1 = SA[(d + 1) * 65 + lane];
            const float xA0 = XS[xb + d],      xA1 = XS[xb + d + 1];
            const float xB0 = XS[xb + 64 + d], xB1 = XS[xb + 64 + d + 1];
            da0 = fmaf(xA0, w0, da0);  da1 = fmaf(xA1, w1, da1);
            db0 = fmaf(xB0, w0, db0);  db1 = fmaf(xB1, w1, db1);
        }
        float a2A = aA * aA, a2B = aB * aB;
        wredsum2(a2A, a2B);
        const float b2l = s64v[lane];
        const float twl = tw[lane];
        const float distA = fsq(fmaxf(a2A + b2l - 2.f * (da0 + da1), 1e-12f));
        const float distB = fsq(fmaxf(a2B + b2l - 2.f * (db0 + db1), 1e-12f));
        const float lpA = __logf(distA) - twl;
        const float lpB = __logf(distB) - twl;

        XS[xb + lane]      = lpA;
        XS[xb + 64 + lane] = lpB;
        const float qA = lpA + MARGIN1, qB = lpB + MARGIN1;
        float s00 = 0.f, s01 = 0.f, s10 = 0.f, s11 = 0.f;
        #pragma unroll
        for (int k = 0; k < 64; k += 2) {
            const float lA0 = XS[xb + k],      lA1 = XS[xb + k + 1];
            const float lB0 = XS[xb + 64 + k], lB1 = XS[xb + 64 + k + 1];
            s00 += fmaxf(qA - lA0, 0.f);  s01 += fmaxf(qA - lA1, 0.f);
            s10 += fmaxf(qB - lB0, 0.f);  s11 += fmaxf(qB - lB1, 0.f);
        }
        const float hsA = s00 + s01, hsB = s10 + s11;
        const float cA = (labels[(long)i0 * 64 + lane] > 0) ? hsA : 0.f;
        const float cB = (labels[(long)i1 * 64 + lane] > 0) ? hsB : 0.f;
        wsum = wredsum(cA + cB);
    } else {
        // ================= cl: 1 pair/wave =================
        const int gw = (o - CLS_BLOCKS) * 4 + wid;   // 0..1999 exact
        {
            const int j = tid >> 2, p = tid & 3;
            float s2 = 0.f;
            #pragma unroll
            for (int m = 0; m < 16; ++m) {
                const float e = etag[j * 64 + p * 16 + m];
                s2 += e * e;
                SA[(p * 16 + m) * 65 + j] = e;
            }
            s2 += __shfl_xor(s2, 1); s2 += __shfl_xor(s2, 2);
            if (p == 0) s64v[j] = s2;
        }
        __syncthreads();
        const int ai = imp[gw * 2];
        const int bi = imp[gw * 2 + 1];
        const float y2l = s64v[lane];
        const float x2  = s64v[ai];
        float c0 = 0.f, c1 = 0.f, c2 = 0.f, c3 = 0.f;
        #pragma unroll
        for (int d = 0; d < 64; d += 4) {
            c0 = fmaf(SA[(d)     * 65 + ai], SA[(d)     * 65 + lane], c0);
            c1 = fmaf(SA[(d + 1) * 65 + ai], SA[(d + 1) * 65 + lane], c1);
            c2 = fmaf(SA[(d + 2) * 65 + ai], SA[(d + 2) * 65 + lane], c2);
            c3 = fmaf(SA[(d + 3) * 65 + ai], SA[(d + 3) * 65 + lane], c3);
        }
        const float c   = (c0 + c1) + (c2 + c3);
        const float A   = 1.f - 2.f * c + y2l;
        const float Bc  = 1.f - x2;
        const float nn  = A * A * x2 - 2.f * A * Bc * c + Bc * Bc * y2l;
        const float den = fmaxf(1.f - 2.f * c + x2 * y2l, 1e-15f);
        float n = fsq(fmaxf(nn * frc(den * den), 1e-15f));
        n = fminf(n, MAXNORM);
        const float dd = __logf((1.f + n) * frc(1.f - n));   // 2*artanh(n)
        float dist = dd * dd;
        if (lane == ai) dist = 0.f;        // self-distance: ref < 1e-9 -> masked
        const float logit = (dist > 1e-9f) ? (-dist * (1.f / TAU)) : -1e30f;
        const float dp = bcast(dist, bi);
        const float lp = bcast(logit, bi);
        const float m  = wredmax(logit);
        const float se = wredsum(__expf(logit - m)) + __expf(lp - m);
        wsum = m + __logf(se) + dp * (1.f / TAU);
    }

    if (lane == 0) red4[wid] = wsum;
    __syncthreads();
    if (tid == 0) part[b] = red4[0] + red4[1] + red4[2] + red4[3];
}

__global__ __launch_bounds__(256) void final_reduce(
        const float* __restrict__ parts, int n, float* __restrict__ out) {
    __shared__ double red[256];
    double s = 0.0;
    for (int i = threadIdx.x; i < n; i += 256) s += (double)parts[i];
    red[threadIdx.x] = s;
    __syncthreads();
    for (int off = 128; off > 0; off >>= 1) {
        if (threadIdx.x < off) red[threadIdx.x] += red[threadIdx.x + off];
        __syncthreads();
    }
    if (threadIdx.x == 0) out[0] = (float)red[0];
}

} // namespace

extern "C" void kernel_launch(void* const* d_in, const int* in_sizes, int n_in,
                              void* d_out, int out_size, void* d_ws, size_t ws_size,
                              hipStream_t stream) {
    const float* emb    = (const float*)d_in[0];
    const float* vtg    = (const float*)d_in[1];
    const float* etag   = (const float*)d_in[2];
    const float* linw   = (const float*)d_in[3];
    const float* linb   = (const float*)d_in[4];
    const float* tw     = (const float*)d_in[5];
    const int*   tri    = (const int*)d_in[6];
    const int*   labels = (const int*)d_in[7];
    const int*   imp    = (const int*)d_in[8];
    float* parts = (float*)d_ws;

    fused_kernel<<<NBLK, 256, 0, stream>>>(emb, tri, vtg, etag, linw, linb,
                                           tw, labels, imp, parts);
    final_reduce<<<1, 256, 0, stream>>>(parts, NBLK, (float*)d_out);
}